// Round 25
// baseline (566.967 us; speedup 1.0000x reference)
//
#include <hip/hip_runtime.h>
#include <stdint.h>

#define SS 13
#define P2 169
#define P4 28561
#define NWG 676   // P2 * 4

using half8  = __attribute__((ext_vector_type(8))) _Float16;
using f32x16 = __attribute__((ext_vector_type(16))) float;

__device__ inline f32x16 mfma16(half8 a, half8 b, f32x16 c) {
    return __builtin_amdgcn_mfma_f32_32x32x16_f16(a, b, c, 0, 0, 0);
}

// async global->LDS, 16B per lane; LDS dest = uniform base + lane*16
#define GLOAD16(g, l) __builtin_amdgcn_global_load_lds( \
    (const __attribute__((address_space(1))) void*)(g), \
    (__attribute__((address_space(3))) void*)(l), 16, 0, 0)

// Padded-plane layout (all conv inputs):
//   xN[b][hbp 0..14][wbp 0..14][ch = ci/16][slab 6144B]
//   slab: row pa (0..191, rows>=169 zero), 32B = 16 f16 ci; border planes zero.
//   swizzle: byte_in_slab = (pa*32 + q*16) ^ (((pa>>2)&1)<<4), q = ci_half/8

// ---------------------------------------------------------------------------
// probe_pi: MFMA A<->B k-label pairing, computed ONCE (lane-independent).
// ---------------------------------------------------------------------------
__global__ void probe_pi(int* __restrict__ piArr)
{
    const int lane = threadIdx.x & 63;
    const int kb = lane >> 5;
    for (int jj = 0; jj < 16; jj++) {
        half8 a, bl;
#pragma unroll
        for (int e = 0; e < 8; e++) {
            int lab = kb * 8 + e;
            a[e]  = (_Float16)((lab == jj) ? 1.0f : 0.0f);
            bl[e] = (_Float16)(float)lab;
        }
        f32x16 d = mfma16(a, bl, (f32x16)(0.0f));
        if (lane == 0) piArr[jj] = (int)(d[0] + 0.5f);
    }
}

// ---------------------------------------------------------------------------
// prep_x: x [b][ci 16][pa][hw] fp32 -> xN0 (padded layout, fp16, 1 chunk)
// ---------------------------------------------------------------------------
__global__ void prep_x(const float* __restrict__ x, _Float16* __restrict__ xN)
{
    __shared__ float xt[16 * P2];
    const int pa = blockIdx.x, b = blockIdx.y, t = threadIdx.x;
    for (int idx = t; idx < 16 * P2; idx += 256) {
        int ci = idx / P2, hw = idx - ci * P2;
        xt[idx] = x[(((size_t)b * 16 + ci) * P2 + pa) * P2 + hw];
    }
    __syncthreads();
    for (int hw = t; hw < P2; hw += 256) {
        half8 h0, h1;
#pragma unroll
        for (int e = 0; e < 8; e++) {
            h0[e] = (_Float16)xt[e * P2 + hw];
            h1[e] = (_Float16)xt[(8 + e) * P2 + hw];
        }
        _Float16* slab = xN + (size_t)(b * 225 + (hw / SS + 1) * 15 + (hw % SS + 1)) * 3072;
        int sw = (pa >> 2) & 1;
        *(half8*)&slab[pa * 16 + (sw ? 8 : 0)] = h0;
        *(half8*)&slab[pa * 16 + (sw ? 0 : 8)] = h1;
    }
}

// ---------------------------------------------------------------------------
// norm_pass: y [b][hw][pa][CIN] fp32 -> xN (padded layout, GN+ReLU folded)
// ---------------------------------------------------------------------------
template<int CIN>
__global__ void norm_pass(const float* __restrict__ y, const float* __restrict__ Ap,
                          const float* __restrict__ Cp, _Float16* __restrict__ xN)
{
    constexpr int NCH = CIN / 16;
    int idx = blockIdx.x * 256 + threadIdx.x;
    if (idx >= 4 * P2 * P2 * NCH) return;
    int ch = idx % NCH; int rest = idx / NCH;
    int pa = rest % P2; rest /= P2;
    int hw = rest % P2; int b = rest / P2;
    const float* src = y + ((size_t)((b * P2 + hw) * P2) + pa) * CIN + ch * 16;
    _Float16* slab = xN +
        ((size_t)((b * 225 + (hw / SS + 1) * 15 + (hw % SS + 1)) * NCH) + ch) * 3072;
    half8 h[2];
#pragma unroll
    for (int q = 0; q < 2; q++) {
        float4 v0 = *(const float4*)(src + q * 8);
        float4 v1 = *(const float4*)(src + q * 8 + 4);
        float vv[8] = {v0.x, v0.y, v0.z, v0.w, v1.x, v1.y, v1.z, v1.w};
#pragma unroll
        for (int e = 0; e < 8; e++) {
            int c = b * CIN + ch * 16 + q * 8 + e;
            h[q][e] = (_Float16)fmaxf(vv[e] * Ap[c] + Cp[c], 0.0f);
        }
    }
    int sw = (pa >> 2) & 1;
    *(half8*)&slab[pa * 16 + (sw ? 8 : 0)] = h[0];
    *(half8*)&slab[pa * 16 + (sw ? 0 : 8)] = h[1];
}

// ---------------------------------------------------------------------------
// Pack weights into plain-fp16 A-fragments using the precomputed pairing.
// Center-tap merge: slot j=13 holds w2[4] + w1[4]; conv4d skips tp==13.
// ---------------------------------------------------------------------------
template<int CIN, int COUT>
__global__ void pack_w(const float* __restrict__ w1, const float* __restrict__ w2,
                       const int* __restrict__ piArr, _Float16* __restrict__ wp)
{
    constexpr int NCH = CIN / 16, NCOT = COUT / 32;
    const int idx = blockIdx.x * 256 + threadIdx.x;

    const int i = idx & 7;
    const int l = (idx >> 3) & 63;
    int rest = idx >> 9;
    const int cot = rest % NCOT; rest /= NCOT;
    const int ch = rest % NCH;
    const int j = rest / NCH;
    const int mylab = ((l >> 5) << 3) | i;

    const int pi = piArr[mylab];
    const int co = cot * 32 + (l & 31);
    const int ci = ch * 16 + pi;
    const float* w = (j < 9) ? w1 : w2;
    const int tap = (j < 9) ? j : j - 9;
    float wv = w[((size_t)co * CIN + ci) * 9 + tap];
    if (j == 13)   // merge w1 center tap into w2 center tap (fp32 sum)
        wv += w1[((size_t)co * CIN + ci) * 9 + 4];
    wp[idx] = (_Float16)wv;
}

// ---------------------------------------------------------------------------
// CenterPivotConv4d: R23 structure (inline B loads) + DEPTH-2 weight-pair
// rotation: tap s+2's a0/a1 issue before tap s's MFMAs.
// ---------------------------------------------------------------------------
template<int CIN, int COUT, typename OUT_T, int NW>
__global__ __launch_bounds__(512, 2) void conv4d(
    const _Float16* __restrict__ xN, const _Float16* __restrict__ wp,
    const float* __restrict__ b1, const float* __restrict__ b2,
    OUT_T* __restrict__ y, float* __restrict__ part)
{
    constexpr int NCH = CIN / 16;
    constexpr int NCOT = COUT / 32;
    constexpr int NPAIR = NCOT / 2;
    constexpr int PH = NW / NPAIR;
    constexpr int MAXPT = (6 + PH - 1) / PH;
    constexpr int GPC = (COUT == 64) ? 2 : 1;

    __shared__ _Float16 tile[9 * 3072];   // 55,296B
    __shared__ float gsum[8];

    // ---- bijective XCD swizzle (m204): contiguous hbwb per XCD ----
    int lin = blockIdx.x + P2 * blockIdx.y;
    {
        constexpr int q = NWG / 8, r = NWG % 8;   // 84, 4
        int xcd = lin & 7, sub = lin >> 3;
        lin = (xcd < r) ? xcd * (q + 1) + sub
                        : r * (q + 1) + (xcd - r) * q + sub;
    }
    const int hbwb = lin % P2;
    const int b = lin / P2;
    const int hb = hbwb / SS, wb = hbwb - hb * SS;

    const int t = threadIdx.x;
    const int lane = t & 63;
    const int w = t >> 6;
    const int pr = w % NPAIR;
    const int ph = w / NPAIR;
    const int l31 = lane & 31, kb = lane >> 5;

    if (t < 8) gsum[t] = 0.f;   // synchronized by first loop barrier

    f32x16 acc[2][MAXPT];
#pragma unroll
    for (int c = 0; c < 2; c++)
#pragma unroll
        for (int k = 0; k < MAXPT; k++) acc[c][k] = (f32x16)(0.0f);

    int rowc[MAXPT], haS[MAXPT], waS[MAXPT];
    bool pvS[MAXPT], vpt[MAXPT];
#pragma unroll
    for (int k = 0; k < MAXPT; k++) {
        int p = ph + k * PH;
        vpt[k] = (p < 6);
        int pa = p * 32 + l31;
        rowc[k] = (pa < 175) ? pa : 175;   // rows >=169 are zero in xN
        int ha = pa / SS;
        haS[k] = ha; waS[k] = pa - ha * SS;
        pvS[k] = pa < P2;
    }

    half8 h8z;
#pragma unroll
    for (int e = 0; e < 8; e++) h8z[e] = (_Float16)0.0f;

    for (int ch = 0; ch < NCH; ch++) {
        __syncthreads();
        // ---- stage: 54 x global_load_lds(1024B); padding pre-materialized ----
        for (int id = w; id < 54; id += NW) {
            int j = id / 6, sub = id - j * 6;
            const char* src = (const char*)xN
                + ((size_t)((b * 225 + (hb + j / 3) * 15 + (wb + j % 3)) * NCH) + ch) * 6144
                + sub * 1024 + (size_t)lane * 16;
            char* dst = (char*)tile + j * 6144 + sub * 1024;
            GLOAD16(src, dst);
        }
        __syncthreads();

        // ---- compute: 17 taps (tp==13 merged into tp==4); depth-2 weight
        //      rotation, B-fragments loaded inline (R23 style) ----
        auto waddr = [&](int s) -> const half8* {
            int tpv = (s < 13) ? s : s + 1;
            int wpj = (tpv < 9) ? (9 + tpv) : (tpv - 9);
            return (const half8*)wp +
                ((((size_t)wpj * NCH + ch) * NCOT + pr * 2) * 64 + lane);
        };
        const half8* p0 = waddr(0);
        half8 w00 = p0[0], w01 = p0[64];
        const half8* p1 = waddr(1);
        half8 w10 = p1[0], w11 = p1[64];
        for (int s = 0; s < 17; s++) {
            half8 m0 = w10, m1 = w11;          // placeholder for s+2
            if (s + 2 < 17) {
                const half8* pn = waddr(s + 2);
                m0 = pn[0];
                m1 = pn[64];
            }
            const int tp = (s < 13) ? s : s + 1;
            int dh = 0, dw = 0, plane = tp;
            if (tp >= 9) { int j = tp - 9; dh = j / 3 - 1; dw = (j % 3) - 1; plane = 4; }
            const char* pb = (const char*)tile + plane * 6144;
#pragma unroll
            for (int k = 0; k < MAXPT; k++) {
                if (!vpt[k]) continue;              // wave-uniform
                int row; bool ok = true;
                if (tp < 9) {
                    row = rowc[k];
                } else {
                    int h2 = haS[k] + dh, w2v = waS[k] + dw;
                    ok = pvS[k] && ((unsigned)h2 < SS) && ((unsigned)w2v < SS);
                    row = ok ? h2 * SS + w2v : 0;
                }
                half8 bf = *(const half8*)(pb + ((row * 32 + kb * 16) ^ (((row >> 2) & 1) << 4)));
                if (tp >= 9 && !ok) bf = h8z;
                acc[0][k] = mfma16(w00, bf, acc[0][k]);
                acc[1][k] = mfma16(w01, bf, acc[1][k]);
            }
            w00 = w10; w01 = w11;
            w10 = m0;  w11 = m1;
        }
    }

    // ---- probe composite C/D output maps ----
    int pk[16];
    {
        half8 av, ov;
#pragma unroll
        for (int e = 0; e < 8; e++) {
            av[e] = (_Float16)(float)l31;
            ov[e] = (_Float16)1.0f;
        }
        f32x16 d1 = mfma16(av, ov, (f32x16)(0.0f));   // 16 * m-label
        f32x16 d2 = mfma16(ov, av, (f32x16)(0.0f));   // 16 * n-label
#pragma unroll
        for (int r = 0; r < 16; r++)
            pk[r] = ((int)(d1[r] * (1.0f / 16.0f) + 0.5f))
                  | (((int)(d2[r] * (1.0f / 16.0f) + 0.5f)) << 8);
    }

    // ---- epilogue: bias + store + per-block stats partials ----
    float s1[2][GPC], s2[2][GPC];
#pragma unroll
    for (int c2 = 0; c2 < 2; c2++)
#pragma unroll
        for (int g = 0; g < GPC; g++) { s1[c2][g] = 0.f; s2[c2][g] = 0.f; }

#pragma unroll
    for (int c2 = 0; c2 < 2; c2++) {
        const int cot = pr * 2 + c2;
#pragma unroll
        for (int k = 0; k < MAXPT; k++) {
            if (!vpt[k]) continue;
            const int pt = ph + k * PH;
#pragma unroll
            for (int r = 0; r < 16; r++) {
                int cof = pk[r] & 255;
                int co = cot * 32 + cof;
                int pa = pt * 32 + (pk[r] >> 8);
                if (pa < P2) {
                    float v = acc[c2][k][r] + b1[co] + b2[co];
                    if (GPC == 2) {          // compile-time-indexed (rule #20)
                        bool hi = (cof & 16);
                        s1[c2][0] += hi ? 0.f : v;
                        s1[c2][1] += hi ? v : 0.f;
                        s2[c2][0] += hi ? 0.f : v * v;
                        s2[c2][1] += hi ? v * v : 0.f;
                    } else {
                        s1[c2][0] += v;
                        s2[c2][0] += v * v;
                    }
                    y[((size_t)(b * P2 + hbwb) * P2 + pa) * COUT + co] = (OUT_T)v;
                }
            }
        }
    }

#pragma unroll
    for (int c2 = 0; c2 < 2; c2++)
#pragma unroll
        for (int g = 0; g < GPC; g++) {
            float a = s1[c2][g], q = s2[c2][g];
            for (int off = 32; off; off >>= 1) {
                a += __shfl_down(a, off);
                q += __shfl_down(q, off);
            }
            if (lane == 0) {
                int cot = pr * 2 + c2;
                int grp = (cot * 32 + g * 16) / (COUT / 4);
                atomicAdd(&gsum[grp * 2], a);        // LDS atomics: cheap
                atomicAdd(&gsum[grp * 2 + 1], q);
            }
        }
    __syncthreads();
    if (t < 8)
        part[((size_t)(b * P2 + hbwb)) * 8 + t] = gsum[t];   // unique slot/block
}

// ---------------------------------------------------------------------------
// Reduce per-block partials -> per-(b,c) affine A,C
// ---------------------------------------------------------------------------
template<int COUT>
__global__ void stats_fin(const float* __restrict__ part,
                          const float* __restrict__ gs, const float* __restrict__ gb,
                          float* __restrict__ Aarr, float* __restrict__ Carr)
{
    int i = threadIdx.x + blockIdx.x * blockDim.x;
    if (i >= 4 * COUT) return;
    int b = i / COUT, c = i - b * COUT;
    int grp = c / (COUT / 4);
    float s1 = 0.f, s2 = 0.f;
    const float* p = part + (size_t)(b * P2) * 8 + grp * 2;
    for (int hw = 0; hw < P2; hw++) {
        s1 += p[(size_t)hw * 8];
        s2 += p[(size_t)hw * 8 + 1];
    }
    float cnt = (float)((COUT / 4) * P4);
    float m = s1 / cnt;
    float var = s2 / cnt - m * m;
    float r = rsqrtf(var + 1e-5f);
    float A = r * gs[c];
    Aarr[i] = A;
    Carr[i] = gb[c] - m * A;
}

// ---------------------------------------------------------------------------
// out[b,co,pa,hb] = mean_wb relu(A*y3 + C);  y3 layout [b][hbwb][pa][256] f16
// ---------------------------------------------------------------------------
__global__ void mean_out(const _Float16* __restrict__ y3,
                         const float* __restrict__ Aarr, const float* __restrict__ Carr,
                         float* __restrict__ out)
{
    const int pa = blockIdx.x, b = blockIdx.y, co = threadIdx.x;
    const float A = Aarr[b * 256 + co], C = Carr[b * 256 + co];
    const _Float16* base = y3 + ((size_t)(b * P2) * P2 + pa) * 256 + co;
    float* ob = out + ((size_t)(b * 256 + co) * P2 + pa) * SS;
    for (int hbv = 0; hbv < SS; hbv++) {
        float s = 0.f;
#pragma unroll
        for (int wbv = 0; wbv < SS; wbv++) {
            float v = (float)base[(size_t)(hbv * SS + wbv) * P2 * 256];
            s += fmaxf(v * A + C, 0.f);
        }
        ob[hbv] = s * (1.f / SS);
    }
}

// ---------------------------------------------------------------------------
extern "C" void kernel_launch(void* const* d_in, const int* in_sizes, int n_in,
                              void* d_out, int out_size, void* d_ws, size_t ws_size,
                              hipStream_t stream)
{
    const float* x = (const float*)d_in[0];
    const float *w1[3], *bb1[3], *w2[3], *bb2[3], *gs[3], *gb[3];
    for (int i = 0; i < 3; i++) {
        w1[i]  = (const float*)d_in[1 + 6 * i];
        bb1[i] = (const float*)d_in[2 + 6 * i];
        w2[i]  = (const float*)d_in[3 + 6 * i];
        bb2[i] = (const float*)d_in[4 + 6 * i];
        gs[i]  = (const float*)d_in[5 + 6 * i];
        gb[i]  = (const float*)d_in[6 + 6 * i];
    }
    float* out = (float*)d_out;
    char* ws = (char*)d_ws;

    float* A0 = (float*)(ws + 4096);
    float* C0 = (float*)(ws + 8192);
    float* A1 = (float*)(ws + 12288);
    float* C1 = (float*)(ws + 16384);
    float* A2 = (float*)(ws + 20480);
    float* C2 = (float*)(ws + 24576);
    int*   piArr = (int*)(ws + 28672);            // 16 ints, written every call
    _Float16* wp1 = (_Float16*)(ws + 32768);
    _Float16* wp2 = (_Float16*)(ws + 196608);
    _Float16* wp3 = (_Float16*)(ws + 1572864);
    // per-block stats partials: 676 * 8 floats = 21,632 B each
    float* part0 = (float*)(ws + 524288);
    float* part1 = (float*)(ws + 548864);
    float* part2 = (float*)(ws + 573440);

    // xN slabs: 4 * 225 * NCH * 6144 bytes
    _Float16* xN0 = (_Float16*)(ws + 8388608);    //  5,529,600 B
    float*    y1  = (float*)(ws + 16777216);      // 29,246,464 B
    _Float16* xN1 = (_Float16*)(ws + 50331648);   // 22,118,400 B
    float*    y2  = (float*)(ws + 75497472);      // 58,492,928 B
    _Float16* xN2 = (_Float16*)(ws + 8388608);    // 44,236,800 B (over dead xN0/y1)
    _Float16* y3  = (_Float16*)(ws + 75497472);   // 29,246,464 B (over dead y2)

    probe_pi<<<1, 64, 0, stream>>>(piArr);
    pack_w<16, 64><<<72, 256, 0, stream>>>(w1[0], w2[0], piArr, wp1);
    pack_w<64, 128><<<576, 256, 0, stream>>>(w1[1], w2[1], piArr, wp2);
    pack_w<128, 256><<<2304, 256, 0, stream>>>(w1[2], w2[2], piArr, wp3);

    // layer 1 (6 waves: COUT=64 -> only ph<6 computes)
    hipMemsetAsync(xN0, 0, (size_t)4 * 225 * 1 * 6144, stream);
    prep_x<<<dim3(P2, 4), 256, 0, stream>>>(x, xN0);
    conv4d<16, 64, float, 6><<<dim3(P2, 4), 384, 0, stream>>>(
        xN0, wp1, bb1[0], bb2[0], y1, part0);
    stats_fin<64><<<1, 256, 0, stream>>>(part0, gs[0], gb[0], A0, C0);

    // layer 2
    hipMemsetAsync(xN1, 0, (size_t)4 * 225 * 4 * 6144, stream);
    norm_pass<64><<<(4 * P2 * P2 * 4 + 255) / 256, 256, 0, stream>>>(y1, A0, C0, xN1);
    conv4d<64, 128, float, 8><<<dim3(P2, 4), 512, 0, stream>>>(
        xN1, wp2, bb1[1], bb2[1], y2, part1);
    stats_fin<128><<<2, 256, 0, stream>>>(part1, gs[1], gb[1], A1, C1);

    // layer 3 (xN2 overlaps dead xN0/y1 -> memset only after conv2 done)
    hipMemsetAsync(xN2, 0, (size_t)4 * 225 * 8 * 6144, stream);
    norm_pass<128><<<(4 * P2 * P2 * 8 + 255) / 256, 256, 0, stream>>>(y2, A1, C1, xN2);
    conv4d<128, 256, _Float16, 8><<<dim3(P2, 4), 512, 0, stream>>>(
        xN2, wp3, bb1[2], bb2[2], y3, part2);
    stats_fin<256><<<4, 256, 0, stream>>>(part2, gs[2], gb[2], A2, C2);

    mean_out<<<dim3(P2, 4), 256, 0, stream>>>(y3, A2, C2, out);
}

// Round 26
// 460.592 us; speedup vs baseline: 1.2310x; 1.2310x over previous
//
#include <hip/hip_runtime.h>
#include <stdint.h>

#define SS 13
#define P2 169
#define P4 28561
#define NWG 676   // P2 * 4

using half8  = __attribute__((ext_vector_type(8))) _Float16;
using f32x16 = __attribute__((ext_vector_type(16))) float;

__device__ inline f32x16 mfma16(half8 a, half8 b, f32x16 c) {
    return __builtin_amdgcn_mfma_f32_32x32x16_f16(a, b, c, 0, 0, 0);
}

// async global->LDS, 16B per lane; LDS dest = uniform base + lane*16
#define GLOAD16(g, l) __builtin_amdgcn_global_load_lds( \
    (const __attribute__((address_space(1))) void*)(g), \
    (__attribute__((address_space(3))) void*)(l), 16, 0, 0)

// Padded-plane layout (all conv inputs):
//   xN[b][hbp 0..14][wbp 0..14][ch = ci/16][slab 6144B]
//   slab: row pa (0..191, rows>=169 zero), 32B = 16 f16 ci; border planes zero.
//   swizzle: byte_in_slab = (pa*32 + q*16) ^ (((pa>>2)&1)<<4), q = ci_half/8

// ---------------------------------------------------------------------------
// probe_pi: MFMA A<->B k-label pairing, computed ONCE (lane-independent).
// ---------------------------------------------------------------------------
__global__ void probe_pi(int* __restrict__ piArr)
{
    const int lane = threadIdx.x & 63;
    const int kb = lane >> 5;
    for (int jj = 0; jj < 16; jj++) {
        half8 a, bl;
#pragma unroll
        for (int e = 0; e < 8; e++) {
            int lab = kb * 8 + e;
            a[e]  = (_Float16)((lab == jj) ? 1.0f : 0.0f);
            bl[e] = (_Float16)(float)lab;
        }
        f32x16 d = mfma16(a, bl, (f32x16)(0.0f));
        if (lane == 0) piArr[jj] = (int)(d[0] + 0.5f);
    }
}

// ---------------------------------------------------------------------------
// prep_x: x [b][ci 16][pa][hw] fp32 -> xN0 (padded layout, fp16, 1 chunk)
// ---------------------------------------------------------------------------
__global__ void prep_x(const float* __restrict__ x, _Float16* __restrict__ xN)
{
    __shared__ float xt[16 * P2];
    const int pa = blockIdx.x, b = blockIdx.y, t = threadIdx.x;
    for (int idx = t; idx < 16 * P2; idx += 256) {
        int ci = idx / P2, hw = idx - ci * P2;
        xt[idx] = x[(((size_t)b * 16 + ci) * P2 + pa) * P2 + hw];
    }
    __syncthreads();
    for (int hw = t; hw < P2; hw += 256) {
        half8 h0, h1;
#pragma unroll
        for (int e = 0; e < 8; e++) {
            h0[e] = (_Float16)xt[e * P2 + hw];
            h1[e] = (_Float16)xt[(8 + e) * P2 + hw];
        }
        _Float16* slab = xN + (size_t)(b * 225 + (hw / SS + 1) * 15 + (hw % SS + 1)) * 3072;
        int sw = (pa >> 2) & 1;
        *(half8*)&slab[pa * 16 + (sw ? 8 : 0)] = h0;
        *(half8*)&slab[pa * 16 + (sw ? 0 : 8)] = h1;
    }
}

// ---------------------------------------------------------------------------
// norm_pass: y [b][hw][pa][CIN] fp32 -> xN (padded layout, GN+ReLU folded)
// ---------------------------------------------------------------------------
template<int CIN>
__global__ void norm_pass(const float* __restrict__ y, const float* __restrict__ Ap,
                          const float* __restrict__ Cp, _Float16* __restrict__ xN)
{
    constexpr int NCH = CIN / 16;
    int idx = blockIdx.x * 256 + threadIdx.x;
    if (idx >= 4 * P2 * P2 * NCH) return;
    int ch = idx % NCH; int rest = idx / NCH;
    int pa = rest % P2; rest /= P2;
    int hw = rest % P2; int b = rest / P2;
    const float* src = y + ((size_t)((b * P2 + hw) * P2) + pa) * CIN + ch * 16;
    _Float16* slab = xN +
        ((size_t)((b * 225 + (hw / SS + 1) * 15 + (hw % SS + 1)) * NCH) + ch) * 3072;
    half8 h[2];
#pragma unroll
    for (int q = 0; q < 2; q++) {
        float4 v0 = *(const float4*)(src + q * 8);
        float4 v1 = *(const float4*)(src + q * 8 + 4);
        float vv[8] = {v0.x, v0.y, v0.z, v0.w, v1.x, v1.y, v1.z, v1.w};
#pragma unroll
        for (int e = 0; e < 8; e++) {
            int c = b * CIN + ch * 16 + q * 8 + e;
            h[q][e] = (_Float16)fmaxf(vv[e] * Ap[c] + Cp[c], 0.0f);
        }
    }
    int sw = (pa >> 2) & 1;
    *(half8*)&slab[pa * 16 + (sw ? 8 : 0)] = h[0];
    *(half8*)&slab[pa * 16 + (sw ? 0 : 8)] = h[1];
}

// ---------------------------------------------------------------------------
// Pack weights into plain-fp16 A-fragments using the precomputed pairing.
// Center-tap merge: slot j=13 holds w2[4] + w1[4]; conv4d skips tp==13.
// ---------------------------------------------------------------------------
template<int CIN, int COUT>
__global__ void pack_w(const float* __restrict__ w1, const float* __restrict__ w2,
                       const int* __restrict__ piArr, _Float16* __restrict__ wp)
{
    constexpr int NCH = CIN / 16, NCOT = COUT / 32;
    const int idx = blockIdx.x * 256 + threadIdx.x;

    const int i = idx & 7;
    const int l = (idx >> 3) & 63;
    int rest = idx >> 9;
    const int cot = rest % NCOT; rest /= NCOT;
    const int ch = rest % NCH;
    const int j = rest / NCH;
    const int mylab = ((l >> 5) << 3) | i;

    const int pi = piArr[mylab];
    const int co = cot * 32 + (l & 31);
    const int ci = ch * 16 + pi;
    const float* w = (j < 9) ? w1 : w2;
    const int tap = (j < 9) ? j : j - 9;
    float wv = w[((size_t)co * CIN + ci) * 9 + tap];
    if (j == 13)   // merge w1 center tap into w2 center tap (fp32 sum)
        wv += w1[((size_t)co * CIN + ci) * 9 + 4];
    wp[idx] = (_Float16)wv;
}

// ---------------------------------------------------------------------------
// CenterPivotConv4d: drained-barrier staging, T1 XCD swizzle, fused
// contention-free GN-stats, depth-1 weight-fragment prefetch (R23 optimum).
// ---------------------------------------------------------------------------
template<int CIN, int COUT, typename OUT_T, int NW>
__global__ __launch_bounds__(512, 2) void conv4d(
    const _Float16* __restrict__ xN, const _Float16* __restrict__ wp,
    const float* __restrict__ b1, const float* __restrict__ b2,
    OUT_T* __restrict__ y, float* __restrict__ part)
{
    constexpr int NCH = CIN / 16;
    constexpr int NCOT = COUT / 32;
    constexpr int NPAIR = NCOT / 2;
    constexpr int PH = NW / NPAIR;
    constexpr int MAXPT = (6 + PH - 1) / PH;
    constexpr int GPC = (COUT == 64) ? 2 : 1;

    __shared__ _Float16 tile[9 * 3072];   // 55,296B
    __shared__ float gsum[8];

    // ---- bijective XCD swizzle (m204): contiguous hbwb per XCD ----
    int lin = blockIdx.x + P2 * blockIdx.y;
    {
        constexpr int q = NWG / 8, r = NWG % 8;   // 84, 4
        int xcd = lin & 7, sub = lin >> 3;
        lin = (xcd < r) ? xcd * (q + 1) + sub
                        : r * (q + 1) + (xcd - r) * q + sub;
    }
    const int hbwb = lin % P2;
    const int b = lin / P2;
    const int hb = hbwb / SS, wb = hbwb - hb * SS;

    const int t = threadIdx.x;
    const int lane = t & 63;
    const int w = t >> 6;
    const int pr = w % NPAIR;
    const int ph = w / NPAIR;
    const int l31 = lane & 31, kb = lane >> 5;

    if (t < 8) gsum[t] = 0.f;   // synchronized by first loop barrier

    f32x16 acc[2][MAXPT];
#pragma unroll
    for (int c = 0; c < 2; c++)
#pragma unroll
        for (int k = 0; k < MAXPT; k++) acc[c][k] = (f32x16)(0.0f);

    int rowc[MAXPT], haS[MAXPT], waS[MAXPT];
    bool pvS[MAXPT], vpt[MAXPT];
#pragma unroll
    for (int k = 0; k < MAXPT; k++) {
        int p = ph + k * PH;
        vpt[k] = (p < 6);
        int pa = p * 32 + l31;
        rowc[k] = (pa < 175) ? pa : 175;   // rows >=169 are zero in xN
        int ha = pa / SS;
        haS[k] = ha; waS[k] = pa - ha * SS;
        pvS[k] = pa < P2;
    }

    half8 h8z;
#pragma unroll
    for (int e = 0; e < 8; e++) h8z[e] = (_Float16)0.0f;

    for (int ch = 0; ch < NCH; ch++) {
        __syncthreads();
        // ---- stage: 54 x global_load_lds(1024B); padding pre-materialized ----
        for (int id = w; id < 54; id += NW) {
            int j = id / 6, sub = id - j * 6;
            const char* src = (const char*)xN
                + ((size_t)((b * 225 + (hb + j / 3) * 15 + (wb + j % 3)) * NCH) + ch) * 6144
                + sub * 1024 + (size_t)lane * 16;
            char* dst = (char*)tile + j * 6144 + sub * 1024;
            GLOAD16(src, dst);
        }
        __syncthreads();

        // ---- compute: 17 taps (tp==13 merged into tp==4), depth-1 weight
        //      prefetch: next tap's fragments load before current MFMAs ----
        auto waddr = [&](int s) -> const half8* {
            int tpv = (s < 13) ? s : s + 1;
            int wpj = (tpv < 9) ? (9 + tpv) : (tpv - 9);
            return (const half8*)wp +
                ((((size_t)wpj * NCH + ch) * NCOT + pr * 2) * 64 + lane);
        };
        const half8* ap0 = waddr(0);
        half8 a0 = ap0[0];
        half8 a1 = ap0[64];
        for (int s = 0; s < 17; s++) {
            half8 a0n = a0, a1n = a1;
            if (s + 1 < 17) {
                const half8* apn = waddr(s + 1);
                a0n = apn[0];
                a1n = apn[64];
            }
            const int tp = (s < 13) ? s : s + 1;
            int dh = 0, dw = 0, plane = tp;
            if (tp >= 9) { int j = tp - 9; dh = j / 3 - 1; dw = (j % 3) - 1; plane = 4; }
            const char* pb = (const char*)tile + plane * 6144;
#pragma unroll
            for (int k = 0; k < MAXPT; k++) {
                if (!vpt[k]) continue;              // wave-uniform
                int row; bool ok = true;
                if (tp < 9) {
                    row = rowc[k];
                } else {
                    int h2 = haS[k] + dh, w2v = waS[k] + dw;
                    ok = pvS[k] && ((unsigned)h2 < SS) && ((unsigned)w2v < SS);
                    row = ok ? h2 * SS + w2v : 0;
                }
                half8 bf = *(const half8*)(pb + ((row * 32 + kb * 16) ^ (((row >> 2) & 1) << 4)));
                if (tp >= 9 && !ok) bf = h8z;
                acc[0][k] = mfma16(a0, bf, acc[0][k]);
                acc[1][k] = mfma16(a1, bf, acc[1][k]);
            }
            a0 = a0n;
            a1 = a1n;
        }
    }

    // ---- probe composite C/D output maps ----
    int pk[16];
    {
        half8 av, ov;
#pragma unroll
        for (int e = 0; e < 8; e++) {
            av[e] = (_Float16)(float)l31;
            ov[e] = (_Float16)1.0f;
        }
        f32x16 d1 = mfma16(av, ov, (f32x16)(0.0f));   // 16 * m-label
        f32x16 d2 = mfma16(ov, av, (f32x16)(0.0f));   // 16 * n-label
#pragma unroll
        for (int r = 0; r < 16; r++)
            pk[r] = ((int)(d1[r] * (1.0f / 16.0f) + 0.5f))
                  | (((int)(d2[r] * (1.0f / 16.0f) + 0.5f)) << 8);
    }

    // ---- epilogue: bias + store + per-block stats partials ----
    float s1[2][GPC], s2[2][GPC];
#pragma unroll
    for (int c2 = 0; c2 < 2; c2++)
#pragma unroll
        for (int g = 0; g < GPC; g++) { s1[c2][g] = 0.f; s2[c2][g] = 0.f; }

#pragma unroll
    for (int c2 = 0; c2 < 2; c2++) {
        const int cot = pr * 2 + c2;
#pragma unroll
        for (int k = 0; k < MAXPT; k++) {
            if (!vpt[k]) continue;
            const int pt = ph + k * PH;
#pragma unroll
            for (int r = 0; r < 16; r++) {
                int cof = pk[r] & 255;
                int co = cot * 32 + cof;
                int pa = pt * 32 + (pk[r] >> 8);
                if (pa < P2) {
                    float v = acc[c2][k][r] + b1[co] + b2[co];
                    if (GPC == 2) {          // compile-time-indexed (rule #20)
                        bool hi = (cof & 16);
                        s1[c2][0] += hi ? 0.f : v;
                        s1[c2][1] += hi ? v : 0.f;
                        s2[c2][0] += hi ? 0.f : v * v;
                        s2[c2][1] += hi ? v * v : 0.f;
                    } else {
                        s1[c2][0] += v;
                        s2[c2][0] += v * v;
                    }
                    y[((size_t)(b * P2 + hbwb) * P2 + pa) * COUT + co] = (OUT_T)v;
                }
            }
        }
    }

#pragma unroll
    for (int c2 = 0; c2 < 2; c2++)
#pragma unroll
        for (int g = 0; g < GPC; g++) {
            float a = s1[c2][g], q = s2[c2][g];
            for (int off = 32; off; off >>= 1) {
                a += __shfl_down(a, off);
                q += __shfl_down(q, off);
            }
            if (lane == 0) {
                int cot = pr * 2 + c2;
                int grp = (cot * 32 + g * 16) / (COUT / 4);
                atomicAdd(&gsum[grp * 2], a);        // LDS atomics: cheap
                atomicAdd(&gsum[grp * 2 + 1], q);
            }
        }
    __syncthreads();
    if (t < 8)
        part[((size_t)(b * P2 + hbwb)) * 8 + t] = gsum[t];   // unique slot/block
}

// ---------------------------------------------------------------------------
// Reduce per-block partials -> per-(b,c) affine A,C
// ---------------------------------------------------------------------------
template<int COUT>
__global__ void stats_fin(const float* __restrict__ part,
                          const float* __restrict__ gs, const float* __restrict__ gb,
                          float* __restrict__ Aarr, float* __restrict__ Carr)
{
    int i = threadIdx.x + blockIdx.x * blockDim.x;
    if (i >= 4 * COUT) return;
    int b = i / COUT, c = i - b * COUT;
    int grp = c / (COUT / 4);
    float s1 = 0.f, s2 = 0.f;
    const float* p = part + (size_t)(b * P2) * 8 + grp * 2;
    for (int hw = 0; hw < P2; hw++) {
        s1 += p[(size_t)hw * 8];
        s2 += p[(size_t)hw * 8 + 1];
    }
    float cnt = (float)((COUT / 4) * P4);
    float m = s1 / cnt;
    float var = s2 / cnt - m * m;
    float r = rsqrtf(var + 1e-5f);
    float A = r * gs[c];
    Aarr[i] = A;
    Carr[i] = gb[c] - m * A;
}

// ---------------------------------------------------------------------------
// out[b,co,pa,hb] = mean_wb relu(A*y3 + C);  y3 layout [b][hbwb][pa][256] f16
// ---------------------------------------------------------------------------
__global__ void mean_out(const _Float16* __restrict__ y3,
                         const float* __restrict__ Aarr, const float* __restrict__ Carr,
                         float* __restrict__ out)
{
    const int pa = blockIdx.x, b = blockIdx.y, co = threadIdx.x;
    const float A = Aarr[b * 256 + co], C = Carr[b * 256 + co];
    const _Float16* base = y3 + ((size_t)(b * P2) * P2 + pa) * 256 + co;
    float* ob = out + ((size_t)(b * 256 + co) * P2 + pa) * SS;
    for (int hbv = 0; hbv < SS; hbv++) {
        float s = 0.f;
#pragma unroll
        for (int wbv = 0; wbv < SS; wbv++) {
            float v = (float)base[(size_t)(hbv * SS + wbv) * P2 * 256];
            s += fmaxf(v * A + C, 0.f);
        }
        ob[hbv] = s * (1.f / SS);
    }
}

// ---------------------------------------------------------------------------
extern "C" void kernel_launch(void* const* d_in, const int* in_sizes, int n_in,
                              void* d_out, int out_size, void* d_ws, size_t ws_size,
                              hipStream_t stream)
{
    const float* x = (const float*)d_in[0];
    const float *w1[3], *bb1[3], *w2[3], *bb2[3], *gs[3], *gb[3];
    for (int i = 0; i < 3; i++) {
        w1[i]  = (const float*)d_in[1 + 6 * i];
        bb1[i] = (const float*)d_in[2 + 6 * i];
        w2[i]  = (const float*)d_in[3 + 6 * i];
        bb2[i] = (const float*)d_in[4 + 6 * i];
        gs[i]  = (const float*)d_in[5 + 6 * i];
        gb[i]  = (const float*)d_in[6 + 6 * i];
    }
    float* out = (float*)d_out;
    char* ws = (char*)d_ws;

    float* A0 = (float*)(ws + 4096);
    float* C0 = (float*)(ws + 8192);
    float* A1 = (float*)(ws + 12288);
    float* C1 = (float*)(ws + 16384);
    float* A2 = (float*)(ws + 20480);
    float* C2 = (float*)(ws + 24576);
    int*   piArr = (int*)(ws + 28672);            // 16 ints, written every call
    _Float16* wp1 = (_Float16*)(ws + 32768);
    _Float16* wp2 = (_Float16*)(ws + 196608);
    _Float16* wp3 = (_Float16*)(ws + 1572864);
    // per-block stats partials: 676 * 8 floats = 21,632 B each
    float* part0 = (float*)(ws + 524288);
    float* part1 = (float*)(ws + 548864);
    float* part2 = (float*)(ws + 573440);

    // xN slabs: 4 * 225 * NCH * 6144 bytes
    _Float16* xN0 = (_Float16*)(ws + 8388608);    //  5,529,600 B
    float*    y1  = (float*)(ws + 16777216);      // 29,246,464 B
    _Float16* xN1 = (_Float16*)(ws + 50331648);   // 22,118,400 B
    float*    y2  = (float*)(ws + 75497472);      // 58,492,928 B
    _Float16* xN2 = (_Float16*)(ws + 8388608);    // 44,236,800 B (over dead xN0/y1)
    _Float16* y3  = (_Float16*)(ws + 75497472);   // 29,246,464 B (over dead y2)

    probe_pi<<<1, 64, 0, stream>>>(piArr);
    pack_w<16, 64><<<72, 256, 0, stream>>>(w1[0], w2[0], piArr, wp1);
    pack_w<64, 128><<<576, 256, 0, stream>>>(w1[1], w2[1], piArr, wp2);
    pack_w<128, 256><<<2304, 256, 0, stream>>>(w1[2], w2[2], piArr, wp3);

    // layer 1 (6 waves: COUT=64 -> only ph<6 computes)
    hipMemsetAsync(xN0, 0, (size_t)4 * 225 * 1 * 6144, stream);
    prep_x<<<dim3(P2, 4), 256, 0, stream>>>(x, xN0);
    conv4d<16, 64, float, 6><<<dim3(P2, 4), 384, 0, stream>>>(
        xN0, wp1, bb1[0], bb2[0], y1, part0);
    stats_fin<64><<<1, 256, 0, stream>>>(part0, gs[0], gb[0], A0, C0);

    // layer 2
    hipMemsetAsync(xN1, 0, (size_t)4 * 225 * 4 * 6144, stream);
    norm_pass<64><<<(4 * P2 * P2 * 4 + 255) / 256, 256, 0, stream>>>(y1, A0, C0, xN1);
    conv4d<64, 128, float, 8><<<dim3(P2, 4), 512, 0, stream>>>(
        xN1, wp2, bb1[1], bb2[1], y2, part1);
    stats_fin<128><<<2, 256, 0, stream>>>(part1, gs[1], gb[1], A1, C1);

    // layer 3 (xN2 overlaps dead xN0/y1 -> memset only after conv2 done)
    hipMemsetAsync(xN2, 0, (size_t)4 * 225 * 8 * 6144, stream);
    norm_pass<128><<<(4 * P2 * P2 * 8 + 255) / 256, 256, 0, stream>>>(y2, A1, C1, xN2);
    conv4d<128, 256, _Float16, 8><<<dim3(P2, 4), 512, 0, stream>>>(
        xN2, wp3, bb1[2], bb2[2], y3, part2);
    stats_fin<256><<<4, 256, 0, stream>>>(part2, gs[2], gb[2], A2, C2);

    mean_out<<<dim3(P2, 4), 256, 0, stream>>>(y3, A2, C2, out);
}